// Round 6
// baseline (551.737 us; speedup 1.0000x reference)
//
#include <hip/hip_runtime.h>
#include <math.h>

#define T_ 128
#define B_ 64
#define H_ 512
#define E_ 256
#define V_ 32000
#define VT_ (V_ + T_)   // 32128
#define UNK_ 2
#define EPS_ 1e-10f

typedef __attribute__((ext_vector_type(8))) __bf16 bf16x8;
typedef __attribute__((ext_vector_type(4))) float floatx4;

// ---------------- K1: fused prologue ----------------
// ranges: zero(score,rawb) | cvt enc->bf16 | cvt attn_W[:,512:] | cvt copy1_W
//         | Wh matvec | gh matvec       (all independent)
#define NB_ZERO 64      // 16384 floats
#define NB_CVTE 2048    // 4,194,304 elems / 8 / 256
#define NB_CVTA 512
#define NB_CVTC 512
#define NB_WH   8192    // 64*512 waves / 4
#define NB_GH   24576   // 64*1536 waves / 4
#define NB_PRO  (NB_ZERO + NB_CVTE + NB_CVTA + NB_CVTC + NB_WH + NB_GH)

__global__ __launch_bounds__(256) void prologue_k(
        const float* __restrict__ u_enc, const float* __restrict__ attn_W,
        const float* __restrict__ copy1_W, const float* __restrict__ last_h,
        const float* __restrict__ attn_b, const float* __restrict__ gru_Whh,
        const float* __restrict__ gru_bhh,
        float* __restrict__ zbase, __bf16* __restrict__ enc_bf,
        __bf16* __restrict__ Wb_attn, __bf16* __restrict__ Wb_copy,
        float* __restrict__ Wh, float* __restrict__ gh) {
    int bid = blockIdx.x, tid = threadIdx.x;
    if (bid < NB_ZERO) { zbase[bid * 256 + tid] = 0.f; return; }
    bid -= NB_ZERO;
    if (bid < NB_CVTE) {
        int i = (bid * 256 + tid) * 8;
        float4 a = *(const float4*)(u_enc + i);
        float4 b = *(const float4*)(u_enc + i + 4);
        bf16x8 o;
        o[0] = (__bf16)a.x; o[1] = (__bf16)a.y; o[2] = (__bf16)a.z; o[3] = (__bf16)a.w;
        o[4] = (__bf16)b.x; o[5] = (__bf16)b.y; o[6] = (__bf16)b.z; o[7] = (__bf16)b.w;
        *(bf16x8*)(enc_bf + i) = o;
        return;
    }
    bid -= NB_CVTE;
    if (bid < NB_CVTA) {
        int c = tid * 2;
        float2 v = *(const float2*)(attn_W + (size_t)bid * 1024 + 512 + c);
        Wb_attn[bid * 512 + c]     = (__bf16)v.x;
        Wb_attn[bid * 512 + c + 1] = (__bf16)v.y;
        return;
    }
    bid -= NB_CVTA;
    if (bid < NB_CVTC) {
        int c = tid * 2;
        float2 v = *(const float2*)(copy1_W + (size_t)bid * 512 + c);
        Wb_copy[bid * 512 + c]     = (__bf16)v.x;
        Wb_copy[bid * 512 + c + 1] = (__bf16)v.y;
        return;
    }
    bid -= NB_CVTC;
    if (bid < NB_WH) {
        int wid = bid * 4 + (tid >> 6), lane = tid & 63;
        int b = wid >> 9, m = wid & 511;
        const float4* wr = (const float4*)(attn_W + (size_t)m * 1024);
        const float4* xr = (const float4*)(last_h + b * 512);
        float s = 0.f;
        #pragma unroll
        for (int i = 0; i < 2; ++i) {
            int k = lane + i * 64;
            float4 w = wr[k], x = xr[k];
            s += w.x * x.x + w.y * x.y + w.z * x.z + w.w * x.w;
        }
        #pragma unroll
        for (int off = 32; off > 0; off >>= 1) s += __shfl_down(s, off);
        if (lane == 0) Wh[b * 512 + m] = s + attn_b[m];
        return;
    }
    bid -= NB_WH;
    {
        int wid = bid * 4 + (tid >> 6), lane = tid & 63;
        int b = wid / 1536, m = wid % 1536;
        const float4* wr = (const float4*)(gru_Whh + (size_t)m * 512);
        const float4* xr = (const float4*)(last_h + b * 512);
        float s = 0.f;
        #pragma unroll
        for (int i = 0; i < 2; ++i) {
            int k = lane + i * 64;
            float4 w = wr[k], x = xr[k];
            s += w.x * x.x + w.y * x.y + w.z * x.z + w.w * x.w;
        }
        #pragma unroll
        for (int off = 32; off > 0; off >>= 1) s += __shfl_down(s, off);
        if (lane == 0) gh[b * 1536 + m] = s + gru_bhh[m];
    }
}

// ------- enc GEMM via bf16 MFMA with fused tanh+dot epilogue -------
__global__ __launch_bounds__(256) void enc_mfma_dot_k(
        const __bf16* __restrict__ enc_bf,  // (T,B,H)
        const __bf16* __restrict__ Wb,      // (512,512) packed
        const float* __restrict__ addv, int add_per_b,
        const float* __restrict__ dotv, int dot_per_b,
        float* __restrict__ out) {          // (B*T), zeroed
    int lane = threadIdx.x & 63;
    int wave = threadIdx.x >> 6;
    int r0 = blockIdx.x * 64;           // global row (b*T + t)
    int b  = r0 / T_;
    int t0 = r0 % T_;
    int n0 = blockIdx.y * 64 + wave * 16;
    int coln = lane & 15;
    int kq   = (lane >> 4) * 8;
    const __bf16* wrow = Wb + (size_t)(n0 + coln) * H_ + kq;
    floatx4 acc[4] = {};
    #pragma unroll 4
    for (int k0 = 0; k0 < H_; k0 += 32) {
        bf16x8 fb = *(const bf16x8*)(wrow + k0);
        #pragma unroll
        for (int mi = 0; mi < 4; ++mi) {
            const __bf16* arow = enc_bf +
                ((size_t)(t0 + mi * 16 + coln) * B_ + b) * H_ + k0 + kq;
            bf16x8 fa = *(const bf16x8*)arow;
            acc[mi] = __builtin_amdgcn_mfma_f32_16x16x32_bf16(fa, fb, acc[mi], 0, 0, 0);
        }
    }
    int col = n0 + coln;
    float addt = add_per_b ? addv[b * H_ + col] : addv[col];
    float dt   = dot_per_b ? dotv[b * H_ + col] : dotv[col];
    int rbase = (lane >> 4) * 4;
    #pragma unroll
    for (int mi = 0; mi < 4; ++mi)
        #pragma unroll
        for (int r = 0; r < 4; ++r) {
            float x = acc[mi][r] + addt;
            float t = __expf(2.f * x);
            float v = dt * ((t - 1.f) / (t + 1.f));
            v += __shfl_xor(v, 1);
            v += __shfl_xor(v, 2);
            v += __shfl_xor(v, 4);
            v += __shfl_xor(v, 8);
            if (coln == 0) atomicAdd(&out[r0 + mi * 16 + rbase + r], v);
        }
}

// ---------------- K3: fused softmax + ctx + gi matvec + GRU (per b) --------
__global__ __launch_bounds__(512) void attn_gru_k(
        const float* __restrict__ score, const float* __restrict__ u_enc,
        const float* __restrict__ emb, const int* __restrict__ z,
        const float* __restrict__ gru_Wih, const float* __restrict__ gru_bih,
        const float* __restrict__ gh, const float* __restrict__ last_h,
        float* __restrict__ ctx, __bf16* __restrict__ xcat_bf,
        float* __restrict__ out) {
    __shared__ float al[T_];
    __shared__ float red[T_];
    __shared__ float gil[1536];
    int b = blockIdx.x, tid = threadIdx.x;
    // --- softmax over T ---
    float v = 0.f;
    if (tid < T_) { v = score[b * T_ + tid]; red[tid] = v; }
    __syncthreads();
    for (int s = 64; s > 0; s >>= 1) { if (tid < s) red[tid] = fmaxf(red[tid], red[tid + s]); __syncthreads(); }
    float cm = red[0];
    __syncthreads();
    if (tid < T_) { float e = __expf(v - cm); al[tid] = e; red[tid] = e; }
    __syncthreads();
    for (int s = 64; s > 0; s >>= 1) { if (tid < s) red[tid] += red[tid + s]; __syncthreads(); }
    float inv = 1.f / red[0];
    __syncthreads();
    if (tid < T_) al[tid] *= inv;
    __syncthreads();
    // --- ctx[h] = sum_t al[t] * enc[t,b,h] ---
    {
        int h = tid;  // 0..511
        float s = 0.f;
        for (int t = 0; t < T_; ++t) s += al[t] * u_enc[((size_t)t * B_ + b) * H_ + h];
        ctx[b * 512 + h] = s;
        xcat_bf[b * 1024 + 512 + h] = (__bf16)s;
    }
    __syncthreads();   // ctx global writes visible to this block
    // --- gi = Wih @ [emb_z, ctx] + bih ---
    {
        int wave = tid >> 6, lane = tid & 63;
        int zb = z[b];
        const float4* ef = (const float4*)(emb) + (size_t)zb * 64;   // 256 floats
        const float4* cf = (const float4*)(ctx + (size_t)b * 512);   // 128 f4
        for (int m = wave; m < 1536; m += 8) {
            const float4* wr = (const float4*)(gru_Wih) + (size_t)m * 192;
            float4 w0 = wr[lane],        x0 = ef[lane];
            float4 w1 = wr[lane + 64],   x1 = cf[lane];
            float4 w2 = wr[lane + 128],  x2 = cf[lane + 64];
            float s = w0.x * x0.x + w0.y * x0.y + w0.z * x0.z + w0.w * x0.w
                    + w1.x * x1.x + w1.y * x1.y + w1.z * x1.z + w1.w * x1.w
                    + w2.x * x2.x + w2.y * x2.y + w2.z * x2.z + w2.w * x2.w;
            #pragma unroll
            for (int off = 32; off > 0; off >>= 1) s += __shfl_down(s, off);
            if (lane == 0) gil[m] = s + gru_bih[m];
        }
    }
    __syncthreads();
    // --- GRU elementwise ---
    {
        int h = tid;
        float ir = gil[h], iz = gil[512 + h], in_ = gil[1024 + h];
        float hr = gh[b * 1536 + h], hz = gh[b * 1536 + 512 + h], hn = gh[b * 1536 + 1024 + h];
        float r = 1.f / (1.f + __expf(-(ir + hr)));
        float zz = 1.f / (1.f + __expf(-(iz + hz)));
        float n = tanhf(in_ + r * hn);
        float hp = last_h[b * 512 + h];
        float hv = (1.f - zz) * n + zz * hp;
        out[b * 512 + h] = hv;                 // gru_out  (also hnew for enc#2)
        out[B_ * 512 + b * 512 + h] = hv;      // new_hidden
        xcat_bf[b * 1024 + h] = (__bf16)hv;
    }
}

// ---------------- gen_score via bf16 MFMA, full-K, direct store --------
__global__ __launch_bounds__(256) void proj_mfma_k(
        const __bf16* __restrict__ xcat_bf, // (64,1024) bf16
        const float* __restrict__ Wp,       // (V,1024) fp32
        const float* __restrict__ bp,       // (V)
        float* __restrict__ gen) {          // (64,V)
    int lane = threadIdx.x & 63;
    int wave = threadIdx.x >> 6;
    int n0 = (blockIdx.x * 4 + wave) * 16;
    int col = lane & 15;
    int kq  = (lane >> 4) * 8;
    const float* wrow = Wp + (size_t)(n0 + col) * 1024 + kq;
    const __bf16* abase = xcat_bf + kq;
    floatx4 acc[4] = {};
    #pragma unroll 8
    for (int k0 = 0; k0 < 1024; k0 += 32) {
        const float4* wb = (const float4*)(wrow + k0);
        float4 b0 = wb[0], b1 = wb[1];
        bf16x8 fb;
        fb[0] = (__bf16)b0.x; fb[1] = (__bf16)b0.y; fb[2] = (__bf16)b0.z; fb[3] = (__bf16)b0.w;
        fb[4] = (__bf16)b1.x; fb[5] = (__bf16)b1.y; fb[6] = (__bf16)b1.z; fb[7] = (__bf16)b1.w;
        #pragma unroll
        for (int mi = 0; mi < 4; ++mi) {
            bf16x8 fa = *(const bf16x8*)(abase + (size_t)(mi * 16 + col) * 1024 + k0);
            acc[mi] = __builtin_amdgcn_mfma_f32_16x16x32_bf16(fa, fb, acc[mi], 0, 0, 0);
        }
    }
    int rbase = (lane >> 4) * 4;
    float bias = bp[n0 + col];
    #pragma unroll
    for (int mi = 0; mi < 4; ++mi)
        #pragma unroll
        for (int r = 0; r < 4; ++r) {
            int b = mi * 16 + rbase + r;
            gen[(size_t)b * V_ + n0 + col] = acc[mi][r] + bias;
        }
}

// ---------------- K6: raw stats + sparse-zero + scatter (per b) ----------
__global__ void copy_epi_k(const float* __restrict__ raw,
                           const int* __restrict__ u_input,
                           float* __restrict__ scat, float* __restrict__ sc4) {
    __shared__ float red[T_];
    int b = blockIdx.x, t = threadIdx.x;
    float v = raw[b * T_ + t];
    red[t] = v; __syncthreads();
    for (int s = 64; s > 0; s >>= 1) { if (t < s) red[t] = fmaxf(red[t], red[t + s]); __syncthreads(); }
    float cm = red[0]; __syncthreads();
    float e = __expf(v - cm);
    red[t] = e; __syncthreads();
    for (int s = 64; s > 0; s >>= 1) { if (t < s) red[t] += red[t + s]; __syncthreads(); }
    float tot = red[0]; __syncthreads();
    int id = u_input[t * B_ + b];
    size_t j = (size_t)b * VT_ + ((id == UNK_) ? (V_ + t) : id);
    if (id != 0) scat[j] = 0.f;
    __syncthreads();
    if (id != 0) atomicAdd(&scat[j], e);
    red[t] = (id != 0) ? e : 0.f; __syncthreads();
    for (int s = 64; s > 0; s >>= 1) { if (t < s) red[t] += red[t + s]; __syncthreads(); }
    float ssum = red[0]; __syncthreads();
    float sv = (id != 0) ? scat[j] : 0.f;
    red[t] = sv; __syncthreads();
    for (int s = 64; s > 0; s >>= 1) { if (t < s) red[t] = fmaxf(red[t], red[t + s]); __syncthreads(); }
    if (t == 0) {
        sc4[b * 4 + 0] = cm;
        sc4[b * 4 + 1] = tot;
        sc4[b * 4 + 2] = ssum;
        sc4[b * 4 + 3] = red[0];   // smax
    }
}

// ---------------- K7: gen row stats -> softmax params (per b) ----------
__global__ __launch_bounds__(1024) void params_k(const float* __restrict__ gen,
                                                 const float* __restrict__ sc4,
                                                 float* __restrict__ params) {
    __shared__ float red[1024];
    int b = blockIdx.x, tid = threadIdx.x;
    const float* gr = gen + (size_t)b * V_;
    float m = -1e30f;
    for (int j = tid; j < V_; j += 1024) m = fmaxf(m, gr[j]);
    red[tid] = m; __syncthreads();
    for (int s = 512; s > 0; s >>= 1) { if (tid < s) red[tid] = fmaxf(red[tid], red[tid + s]); __syncthreads(); }
    float Mg = red[0];
    float cm = sc4[b * 4], tot = sc4[b * 4 + 1], ssum = sc4[b * 4 + 2], smax = sc4[b * 4 + 3];
    float umax = cm + logf(EPS_ * tot + (1.f - EPS_) * smax);
    float M = fmaxf(Mg, umax);
    __syncthreads();
    float l = 0.f;
    for (int j = tid; j < V_; j += 1024) l += __expf(gr[j] - M);
    red[tid] = l; __syncthreads();
    for (int s = 512; s > 0; s >>= 1) { if (tid < s) red[tid] += red[tid + s]; __syncthreads(); }
    if (tid == 0) {
        float coef = __expf(cm - M);
        float Z = red[0] + coef * (EPS_ * tot * (float)VT_ + (1.f - EPS_) * ssum);
        float invZ = 1.f / Z;
        params[b * 4 + 0] = M;
        params[b * 4 + 1] = invZ;
        params[b * 4 + 2] = coef * EPS_ * tot * invZ;      // addc
        params[b * 4 + 3] = coef * (1.f - EPS_) * invZ;    // scoef
    }
}

// ---------------- streamed proba write (no scat read) ----------------
__global__ __launch_bounds__(256) void write_k(const float* __restrict__ gen,
                                               const float* __restrict__ params,
                                               float* __restrict__ proba) {
    int b = blockIdx.y;
    int i4 = blockIdx.x * 256 + threadIdx.x;   // float4 index
    if (i4 >= VT_ / 4) return;
    float M = params[b * 4], invZ = params[b * 4 + 1], addc = params[b * 4 + 2];
    int j = i4 * 4;
    float4 p;
    if (j < V_) {
        float4 g = *(const float4*)(gen + (size_t)b * V_ + j);
        p.x = addc + __expf(g.x - M) * invZ;
        p.y = addc + __expf(g.y - M) * invZ;
        p.z = addc + __expf(g.z - M) * invZ;
        p.w = addc + __expf(g.w - M) * invZ;
    } else {
        p.x = p.y = p.z = p.w = addc;
    }
    *(float4*)(proba + (size_t)b * VT_ + j) = p;
}

// ---------------- overwrite scattered positions with full value ----------
__global__ void fix_k(const float* __restrict__ gen, const float* __restrict__ scat,
                      const int* __restrict__ u_input, const float* __restrict__ params,
                      float* __restrict__ proba) {
    int b = blockIdx.x, t = threadIdx.x;
    int id = u_input[t * B_ + b];
    if (id == 0) return;
    int j = (id == UNK_) ? (V_ + t) : id;
    float M = params[b * 4], invZ = params[b * 4 + 1];
    float addc = params[b * 4 + 2], scoef = params[b * 4 + 3];
    float p = addc + scoef * scat[(size_t)b * VT_ + j];
    if (j < V_) p += __expf(gen[(size_t)b * V_ + j] - M) * invZ;
    proba[(size_t)b * VT_ + j] = p;
}

extern "C" void kernel_launch(void* const* d_in, const int* in_sizes, int n_in,
                              void* d_out, int out_size, void* d_ws, size_t ws_size,
                              hipStream_t stream) {
    const float* u_enc   = (const float*)d_in[0];
    const int*   z_tm1   = (const int*)d_in[1];
    const float* last_h  = (const float*)d_in[2];
    const int*   u_input = (const int*)d_in[3];
    const float* emb     = (const float*)d_in[4];
    const float* attn_W  = (const float*)d_in[5];
    const float* attn_b  = (const float*)d_in[6];
    const float* attn_v  = (const float*)d_in[7];
    const float* gru_Wih = (const float*)d_in[8];
    const float* gru_Whh = (const float*)d_in[9];
    const float* gru_bih = (const float*)d_in[10];
    const float* gru_bhh = (const float*)d_in[11];
    const float* proj_W  = (const float*)d_in[12];
    const float* proj_b  = (const float*)d_in[13];
    const float* copy1_W = (const float*)d_in[14];
    const float* copy1_b = (const float*)d_in[15];
    float* out = (float*)d_out;

    float* ws    = (float*)d_ws;
    float* score = ws;                          // B*T  (zeroed by prologue)
    float* rawb  = score + B_ * T_;             // B*T  (zeroed by prologue)
    float* gen   = rawb + B_ * T_;              // B*V  (direct store)
    float* scat  = gen + (size_t)B_ * V_;       // B*VT (sparse-zeroed)
    float* Wh    = scat + (size_t)B_ * VT_;     // B*H
    float* gh    = Wh + B_ * H_;                // B*1536
    float* ctx   = gh + B_ * 1536;              // B*H
    float* sc4   = ctx + B_ * H_;               // B*4
    float* params= sc4 + B_ * 4;                // B*4
    __bf16* xcat_bf = (__bf16*)(params + B_ * 4);      // 64*1024 bf16
    __bf16* enc_bf  = xcat_bf + B_ * 1024;             // T*B*H bf16
    __bf16* Wb_attn = enc_bf + (size_t)T_ * B_ * H_;   // 512*512
    __bf16* Wb_copy = Wb_attn + H_ * H_;               // 512*512

    prologue_k<<<NB_PRO, 256, 0, stream>>>(u_enc, attn_W, copy1_W, last_h, attn_b,
                                           gru_Whh, gru_bhh,
                                           score, enc_bf, Wb_attn, Wb_copy, Wh, gh);

    dim3 g2(T_ * B_ / 64, H_ / 64);
    enc_mfma_dot_k<<<g2, 256, 0, stream>>>(enc_bf, Wb_attn, Wh, 1, attn_v, 0, score);

    attn_gru_k<<<B_, 512, 0, stream>>>(score, u_enc, emb, z_tm1, gru_Wih, gru_bih,
                                       gh, last_h, ctx, xcat_bf, out);

    proj_mfma_k<<<V_ / 64, 256, 0, stream>>>(xcat_bf, proj_W, proj_b, gen);

    enc_mfma_dot_k<<<g2, 256, 0, stream>>>(enc_bf, Wb_copy, copy1_b, 0, out, 1, rawb);

    copy_epi_k<<<B_, T_, 0, stream>>>(rawb, u_input, scat, sc4);
    params_k<<<B_, 1024, 0, stream>>>(gen, sc4, params);

    float* proba = out + 2 * B_ * H_;
    write_k<<<dim3((VT_ / 4 + 255) / 256, B_), 256, 0, stream>>>(gen, params, proba);
    fix_k<<<B_, T_, 0, stream>>>(gen, scat, u_input, params, proba);
}

// Round 7
// 426.485 us; speedup vs baseline: 1.2937x; 1.2937x over previous
//
#include <hip/hip_runtime.h>
#include <math.h>

#define T_ 128
#define B_ 64
#define H_ 512
#define E_ 256
#define V_ 32000
#define VT_ (V_ + T_)   // 32128
#define UNK_ 2
#define EPS_ 1e-10f
#define NS_ 16          // gen_stats chunks per row (V/NS = 2000)

typedef __attribute__((ext_vector_type(8))) __bf16 bf16x8;
typedef __attribute__((ext_vector_type(4))) float floatx4;

// ---------------- K1: fused prologue ----------------
// ranges: zero(score,rawb) | cvt enc->bf16 | cvt attn_W[:,512:] | cvt copy1_W
//         | Wh matvec | gh matvec       (all independent)
#define NB_ZERO 64      // 16384 floats
#define NB_CVTE 2048    // 4,194,304 elems / 8 / 256
#define NB_CVTA 512
#define NB_CVTC 512
#define NB_WH   8192    // 64*512 waves / 4
#define NB_GH   24576   // 64*1536 waves / 4
#define NB_PRO  (NB_ZERO + NB_CVTE + NB_CVTA + NB_CVTC + NB_WH + NB_GH)

__global__ __launch_bounds__(256) void prologue_k(
        const float* __restrict__ u_enc, const float* __restrict__ attn_W,
        const float* __restrict__ copy1_W, const float* __restrict__ last_h,
        const float* __restrict__ attn_b, const float* __restrict__ gru_Whh,
        const float* __restrict__ gru_bhh,
        float* __restrict__ zbase, __bf16* __restrict__ enc_bf,
        __bf16* __restrict__ Wb_attn, __bf16* __restrict__ Wb_copy,
        float* __restrict__ Wh, float* __restrict__ gh) {
    int bid = blockIdx.x, tid = threadIdx.x;
    if (bid < NB_ZERO) { zbase[bid * 256 + tid] = 0.f; return; }
    bid -= NB_ZERO;
    if (bid < NB_CVTE) {
        int i = (bid * 256 + tid) * 8;
        float4 a = *(const float4*)(u_enc + i);
        float4 b = *(const float4*)(u_enc + i + 4);
        bf16x8 o;
        o[0] = (__bf16)a.x; o[1] = (__bf16)a.y; o[2] = (__bf16)a.z; o[3] = (__bf16)a.w;
        o[4] = (__bf16)b.x; o[5] = (__bf16)b.y; o[6] = (__bf16)b.z; o[7] = (__bf16)b.w;
        *(bf16x8*)(enc_bf + i) = o;
        return;
    }
    bid -= NB_CVTE;
    if (bid < NB_CVTA) {
        int c = tid * 2;
        float2 v = *(const float2*)(attn_W + (size_t)bid * 1024 + 512 + c);
        Wb_attn[bid * 512 + c]     = (__bf16)v.x;
        Wb_attn[bid * 512 + c + 1] = (__bf16)v.y;
        return;
    }
    bid -= NB_CVTA;
    if (bid < NB_CVTC) {
        int c = tid * 2;
        float2 v = *(const float2*)(copy1_W + (size_t)bid * 512 + c);
        Wb_copy[bid * 512 + c]     = (__bf16)v.x;
        Wb_copy[bid * 512 + c + 1] = (__bf16)v.y;
        return;
    }
    bid -= NB_CVTC;
    if (bid < NB_WH) {
        int wid = bid * 4 + (tid >> 6), lane = tid & 63;
        int b = wid >> 9, m = wid & 511;
        const float4* wr = (const float4*)(attn_W + (size_t)m * 1024);
        const float4* xr = (const float4*)(last_h + b * 512);
        float s = 0.f;
        #pragma unroll
        for (int i = 0; i < 2; ++i) {
            int k = lane + i * 64;
            float4 w = wr[k], x = xr[k];
            s += w.x * x.x + w.y * x.y + w.z * x.z + w.w * x.w;
        }
        #pragma unroll
        for (int off = 32; off > 0; off >>= 1) s += __shfl_down(s, off);
        if (lane == 0) Wh[b * 512 + m] = s + attn_b[m];
        return;
    }
    bid -= NB_WH;
    {
        int wid = bid * 4 + (tid >> 6), lane = tid & 63;
        int b = wid / 1536, m = wid % 1536;
        const float4* wr = (const float4*)(gru_Whh + (size_t)m * 512);
        const float4* xr = (const float4*)(last_h + b * 512);
        float s = 0.f;
        #pragma unroll
        for (int i = 0; i < 2; ++i) {
            int k = lane + i * 64;
            float4 w = wr[k], x = xr[k];
            s += w.x * x.x + w.y * x.y + w.z * x.z + w.w * x.w;
        }
        #pragma unroll
        for (int off = 32; off > 0; off >>= 1) s += __shfl_down(s, off);
        if (lane == 0) gh[b * 1536 + m] = s + gru_bhh[m];
    }
}

// ------- enc GEMM via bf16 MFMA with fused tanh+dot epilogue -------
__global__ __launch_bounds__(256) void enc_mfma_dot_k(
        const __bf16* __restrict__ enc_bf,  // (T,B,H)
        const __bf16* __restrict__ Wb,      // (512,512) packed
        const float* __restrict__ addv, int add_per_b,
        const float* __restrict__ dotv, int dot_per_b,
        float* __restrict__ out) {          // (B*T), zeroed
    int lane = threadIdx.x & 63;
    int wave = threadIdx.x >> 6;
    int r0 = blockIdx.x * 64;           // global row (b*T + t)
    int b  = r0 / T_;
    int t0 = r0 % T_;
    int n0 = blockIdx.y * 64 + wave * 16;
    int coln = lane & 15;
    int kq   = (lane >> 4) * 8;
    const __bf16* wrow = Wb + (size_t)(n0 + coln) * H_ + kq;
    floatx4 acc[4] = {};
    #pragma unroll 4
    for (int k0 = 0; k0 < H_; k0 += 32) {
        bf16x8 fb = *(const bf16x8*)(wrow + k0);
        #pragma unroll
        for (int mi = 0; mi < 4; ++mi) {
            const __bf16* arow = enc_bf +
                ((size_t)(t0 + mi * 16 + coln) * B_ + b) * H_ + k0 + kq;
            bf16x8 fa = *(const bf16x8*)arow;
            acc[mi] = __builtin_amdgcn_mfma_f32_16x16x32_bf16(fa, fb, acc[mi], 0, 0, 0);
        }
    }
    int col = n0 + coln;
    float addt = add_per_b ? addv[b * H_ + col] : addv[col];
    float dt   = dot_per_b ? dotv[b * H_ + col] : dotv[col];
    int rbase = (lane >> 4) * 4;
    #pragma unroll
    for (int mi = 0; mi < 4; ++mi)
        #pragma unroll
        for (int r = 0; r < 4; ++r) {
            float x = acc[mi][r] + addt;
            float t = __expf(2.f * x);
            float v = dt * ((t - 1.f) / (t + 1.f));
            v += __shfl_xor(v, 1);
            v += __shfl_xor(v, 2);
            v += __shfl_xor(v, 4);
            v += __shfl_xor(v, 8);
            if (coln == 0) atomicAdd(&out[r0 + mi * 16 + rbase + r], v);
        }
}

// ---------------- alpha = softmax over T per b ----------------
__global__ void softmax_t_k(const float* __restrict__ score, float* __restrict__ alpha) {
    __shared__ float red[T_];
    int b = blockIdx.x, t = threadIdx.x;
    float v = score[b * T_ + t];
    red[t] = v; __syncthreads();
    for (int s = 64; s > 0; s >>= 1) { if (t < s) red[t] = fmaxf(red[t], red[t + s]); __syncthreads(); }
    float m = red[0]; __syncthreads();
    float e = __expf(v - m);
    red[t] = e; __syncthreads();
    for (int s = 64; s > 0; s >>= 1) { if (t < s) red[t] += red[t + s]; __syncthreads(); }
    alpha[b * T_ + t] = e / red[0];
}

// ---------------- ctx = alpha-weighted sum over enc ----------------
__global__ void ctx_k(const float* __restrict__ enc, const float* __restrict__ alpha,
                      float* __restrict__ ctx, __bf16* __restrict__ xcat_bf) {
    __shared__ float al[T_];
    int b = blockIdx.x;
    int h = blockIdx.y * 256 + threadIdx.x;
    if (threadIdx.x < T_) al[threadIdx.x] = alpha[b * T_ + threadIdx.x];
    __syncthreads();
    float s = 0.f;
    for (int t = 0; t < T_; ++t) s += al[t] * enc[((size_t)t * B_ + b) * H_ + h];
    ctx[b * H_ + h] = s;
    xcat_bf[b * 1024 + 512 + h] = (__bf16)s;
}

// gi matvec with gathered x = [emb[z[b]] (E), ctx[b] (H)]
__global__ void gi_matvec_k(const float* __restrict__ Wih,  // (1536, 768)
                            const float* __restrict__ emb,
                            const int* __restrict__ z,
                            const float* __restrict__ ctx,
                            const float* __restrict__ bih,
                            float* __restrict__ gi) {
    const int M = 1536, K = 768;
    int wid  = blockIdx.x * 4 + (threadIdx.x >> 6);
    int lane = threadIdx.x & 63;
    int b = wid / M, m = wid % M;
    if (b >= B_) return;
    const float4* wr = (const float4*)(Wih + (size_t)m * K);
    const float4* er = (const float4*)(emb + (size_t)z[b] * E_);
    const float4* cr = (const float4*)(ctx + (size_t)b * H_);
    float s = 0.f;
    for (int k = lane; k < K / 4; k += 64) {
        float4 xv = (k < E_ / 4) ? er[k] : cr[k - E_ / 4];
        float4 w = wr[k];
        s += w.x * xv.x + w.y * xv.y + w.z * xv.z + w.w * xv.w;
    }
    #pragma unroll
    for (int off = 32; off > 0; off >>= 1) s += __shfl_down(s, off);
    if (lane == 0) gi[b * M + m] = s + bih[m];
}

// ---------------- GRU elementwise ----------------
__global__ void gru_k(const float* __restrict__ gi, const float* __restrict__ gh,
                      const float* __restrict__ hprev,
                      float* __restrict__ out, __bf16* __restrict__ xcat_bf) {
    int b = blockIdx.x;
    int m = blockIdx.y * 256 + threadIdx.x;
    float ir = gi[b * 1536 + m],        hr = gh[b * 1536 + m];
    float iz = gi[b * 1536 + 512 + m],  hz = gh[b * 1536 + 512 + m];
    float in_ = gi[b * 1536 + 1024 + m], hn = gh[b * 1536 + 1024 + m];
    float r = 1.f / (1.f + __expf(-(ir + hr)));
    float z = 1.f / (1.f + __expf(-(iz + hz)));
    float n = tanhf(in_ + r * hn);
    float h = hprev[b * 512 + m];
    float hv = (1.f - z) * n + z * h;
    out[b * 512 + m] = hv;                 // gru_out (also read as hnew by enc#2)
    out[B_ * 512 + b * 512 + m] = hv;      // new_hidden
    xcat_bf[b * 1024 + m] = (__bf16)hv;
}

// ---------------- gen_score via bf16 MFMA, full-K, direct store --------
__global__ __launch_bounds__(256) void proj_mfma_k(
        const __bf16* __restrict__ xcat_bf, // (64,1024) bf16
        const float* __restrict__ Wp,       // (V,1024) fp32
        const float* __restrict__ bp,       // (V)
        float* __restrict__ gen) {          // (64,V)
    int lane = threadIdx.x & 63;
    int wave = threadIdx.x >> 6;
    int n0 = (blockIdx.x * 4 + wave) * 16;
    int col = lane & 15;
    int kq  = (lane >> 4) * 8;
    const float* wrow = Wp + (size_t)(n0 + col) * 1024 + kq;
    const __bf16* abase = xcat_bf + kq;
    floatx4 acc[4] = {};
    #pragma unroll 8
    for (int k0 = 0; k0 < 1024; k0 += 32) {
        const float4* wb = (const float4*)(wrow + k0);
        float4 b0 = wb[0], b1 = wb[1];
        bf16x8 fb;
        fb[0] = (__bf16)b0.x; fb[1] = (__bf16)b0.y; fb[2] = (__bf16)b0.z; fb[3] = (__bf16)b0.w;
        fb[4] = (__bf16)b1.x; fb[5] = (__bf16)b1.y; fb[6] = (__bf16)b1.z; fb[7] = (__bf16)b1.w;
        #pragma unroll
        for (int mi = 0; mi < 4; ++mi) {
            bf16x8 fa = *(const bf16x8*)(abase + (size_t)(mi * 16 + col) * 1024 + k0);
            acc[mi] = __builtin_amdgcn_mfma_f32_16x16x32_bf16(fa, fb, acc[mi], 0, 0, 0);
        }
    }
    int rbase = (lane >> 4) * 4;
    float bias = bp[n0 + col];
    #pragma unroll
    for (int mi = 0; mi < 4; ++mi)
        #pragma unroll
        for (int r = 0; r < 4; ++r) {
            int b = mi * 16 + rbase + r;
            gen[(size_t)b * V_ + n0 + col] = acc[mi][r] + bias;
        }
}

// ---------------- K6: raw stats + sparse-zero + scatter (per b) ----------
__global__ void copy_epi_k(const float* __restrict__ raw,
                           const int* __restrict__ u_input,
                           float* __restrict__ scat, float* __restrict__ sc4) {
    __shared__ float red[T_];
    int b = blockIdx.x, t = threadIdx.x;
    float v = raw[b * T_ + t];
    red[t] = v; __syncthreads();
    for (int s = 64; s > 0; s >>= 1) { if (t < s) red[t] = fmaxf(red[t], red[t + s]); __syncthreads(); }
    float cm = red[0]; __syncthreads();
    float e = __expf(v - cm);
    red[t] = e; __syncthreads();
    for (int s = 64; s > 0; s >>= 1) { if (t < s) red[t] += red[t + s]; __syncthreads(); }
    float tot = red[0]; __syncthreads();
    int id = u_input[t * B_ + b];
    size_t j = (size_t)b * VT_ + ((id == UNK_) ? (V_ + t) : id);
    if (id != 0) scat[j] = 0.f;
    __syncthreads();
    if (id != 0) atomicAdd(&scat[j], e);
    red[t] = (id != 0) ? e : 0.f; __syncthreads();
    for (int s = 64; s > 0; s >>= 1) { if (t < s) red[t] += red[t + s]; __syncthreads(); }
    float ssum = red[0]; __syncthreads();
    float sv = (id != 0) ? scat[j] : 0.f;
    red[t] = sv; __syncthreads();
    for (int s = 64; s > 0; s >>= 1) { if (t < s) red[t] = fmaxf(red[t], red[t + s]); __syncthreads(); }
    if (t == 0) {
        sc4[b * 4 + 0] = cm;
        sc4[b * 4 + 1] = tot;
        sc4[b * 4 + 2] = ssum;
        sc4[b * 4 + 3] = red[0];   // smax
    }
}

// ---------------- gen per-chunk online softmax partials ----------------
__global__ __launch_bounds__(256) void gen_stats_k(const float* __restrict__ gen,
                                                   float* __restrict__ mpart,
                                                   float* __restrict__ lpart) {
    int b = blockIdx.x, s = blockIdx.y, tid = threadIdx.x;
    const int C = V_ / NS_;   // 2000
    const float* gr = gen + (size_t)b * V_ + s * C;
    __shared__ float red[256];
    float m = -1e30f;
    for (int j = tid; j < C; j += 256) m = fmaxf(m, gr[j]);
    red[tid] = m; __syncthreads();
    for (int st = 128; st > 0; st >>= 1) { if (tid < st) red[tid] = fmaxf(red[tid], red[tid + st]); __syncthreads(); }
    m = red[0]; __syncthreads();
    float l = 0.f;
    for (int j = tid; j < C; j += 256) l += __expf(gr[j] - m);
    red[tid] = l; __syncthreads();
    for (int st = 128; st > 0; st >>= 1) { if (tid < st) red[tid] += red[tid + st]; __syncthreads(); }
    if (tid == 0) { mpart[b * NS_ + s] = m; lpart[b * NS_ + s] = red[0]; }
}

// ---------------- combine partials + sc4 -> per-row params (1 block) ------
__global__ void combine2_k(const float* __restrict__ mpart, const float* __restrict__ lpart,
                           const float* __restrict__ sc4, float* __restrict__ params) {
    int b = threadIdx.x;   // 64 threads, one per row
    float Mg = -1e30f;
    #pragma unroll
    for (int s = 0; s < NS_; s++) Mg = fmaxf(Mg, mpart[b * NS_ + s]);
    float cm = sc4[b * 4], tot = sc4[b * 4 + 1], ssum = sc4[b * 4 + 2], smax = sc4[b * 4 + 3];
    float umax = cm + logf(EPS_ * tot + (1.f - EPS_) * smax);
    float M = fmaxf(Mg, umax);
    float Zg = 0.f;
    #pragma unroll
    for (int s = 0; s < NS_; s++) Zg += lpart[b * NS_ + s] * __expf(mpart[b * NS_ + s] - M);
    float coef = __expf(cm - M);
    float Z = Zg + coef * (EPS_ * tot * (float)VT_ + (1.f - EPS_) * ssum);
    float invZ = 1.f / Z;
    params[b * 4 + 0] = M;
    params[b * 4 + 1] = invZ;
    params[b * 4 + 2] = coef * EPS_ * tot * invZ;      // addc
    params[b * 4 + 3] = coef * (1.f - EPS_) * invZ;    // scoef
}

// ---------------- streamed proba write (no scat read) ----------------
__global__ __launch_bounds__(256) void write_k(const float* __restrict__ gen,
                                               const float* __restrict__ params,
                                               float* __restrict__ proba) {
    int b = blockIdx.y;
    int i4 = blockIdx.x * 256 + threadIdx.x;   // float4 index
    if (i4 >= VT_ / 4) return;
    float M = params[b * 4], invZ = params[b * 4 + 1], addc = params[b * 4 + 2];
    int j = i4 * 4;
    float4 p;
    if (j < V_) {
        float4 g = *(const float4*)(gen + (size_t)b * V_ + j);
        p.x = addc + __expf(g.x - M) * invZ;
        p.y = addc + __expf(g.y - M) * invZ;
        p.z = addc + __expf(g.z - M) * invZ;
        p.w = addc + __expf(g.w - M) * invZ;
    } else {
        p.x = p.y = p.z = p.w = addc;
    }
    *(float4*)(proba + (size_t)b * VT_ + j) = p;
}

// ---------------- overwrite scattered positions with full value ----------
__global__ void fix_k(const float* __restrict__ gen, const float* __restrict__ scat,
                      const int* __restrict__ u_input, const float* __restrict__ params,
                      float* __restrict__ proba) {
    int b = blockIdx.x, t = threadIdx.x;
    int id = u_input[t * B_ + b];
    if (id == 0) return;
    int j = (id == UNK_) ? (V_ + t) : id;
    float M = params[b * 4], invZ = params[b * 4 + 1];
    float addc = params[b * 4 + 2], scoef = params[b * 4 + 3];
    float p = addc + scoef * scat[(size_t)b * VT_ + j];
    if (j < V_) p += __expf(gen[(size_t)b * V_ + j] - M) * invZ;
    proba[(size_t)b * VT_ + j] = p;
}

extern "C" void kernel_launch(void* const* d_in, const int* in_sizes, int n_in,
                              void* d_out, int out_size, void* d_ws, size_t ws_size,
                              hipStream_t stream) {
    const float* u_enc   = (const float*)d_in[0];
    const int*   z_tm1   = (const int*)d_in[1];
    const float* last_h  = (const float*)d_in[2];
    const int*   u_input = (const int*)d_in[3];
    const float* emb     = (const float*)d_in[4];
    const float* attn_W  = (const float*)d_in[5];
    const float* attn_b  = (const float*)d_in[6];
    const float* attn_v  = (const float*)d_in[7];
    const float* gru_Wih = (const float*)d_in[8];
    const float* gru_Whh = (const float*)d_in[9];
    const float* gru_bih = (const float*)d_in[10];
    const float* gru_bhh = (const float*)d_in[11];
    const float* proj_W  = (const float*)d_in[12];
    const float* proj_b  = (const float*)d_in[13];
    const float* copy1_W = (const float*)d_in[14];
    const float* copy1_b = (const float*)d_in[15];
    float* out = (float*)d_out;

    float* ws    = (float*)d_ws;
    float* score = ws;                          // B*T  (zeroed by prologue)
    float* rawb  = score + B_ * T_;             // B*T  (zeroed by prologue)
    float* gen   = rawb + B_ * T_;              // B*V  (direct store)
    float* scat  = gen + (size_t)B_ * V_;       // B*VT (sparse-zeroed)
    float* Wh    = scat + (size_t)B_ * VT_;     // B*H
    float* gh    = Wh + B_ * H_;                // B*1536
    float* alpha = gh + B_ * 1536;              // B*T
    float* ctx   = alpha + B_ * T_;             // B*H
    float* gi    = ctx + B_ * H_;               // B*1536
    float* sc4   = gi + B_ * 1536;              // B*4
    float* mpart = sc4 + B_ * 4;                // B*NS
    float* lpart = mpart + B_ * NS_;            // B*NS
    float* params= lpart + B_ * NS_;            // B*4
    __bf16* xcat_bf = (__bf16*)(params + B_ * 4);      // 64*1024 bf16
    __bf16* enc_bf  = xcat_bf + B_ * 1024;             // T*B*H bf16
    __bf16* Wb_attn = enc_bf + (size_t)T_ * B_ * H_;   // 512*512
    __bf16* Wb_copy = Wb_attn + H_ * H_;               // 512*512

    prologue_k<<<NB_PRO, 256, 0, stream>>>(u_enc, attn_W, copy1_W, last_h, attn_b,
                                           gru_Whh, gru_bhh,
                                           score, enc_bf, Wb_attn, Wb_copy, Wh, gh);

    dim3 g2(T_ * B_ / 64, H_ / 64);
    enc_mfma_dot_k<<<g2, 256, 0, stream>>>(enc_bf, Wb_attn, Wh, 1, attn_v, 0, score);

    softmax_t_k<<<B_, T_, 0, stream>>>(score, alpha);
    ctx_k<<<dim3(B_, 2), 256, 0, stream>>>(u_enc, alpha, ctx, xcat_bf);
    gi_matvec_k<<<B_ * 1536 / 4, 256, 0, stream>>>(gru_Wih, emb, z_tm1, ctx, gru_bih, gi);
    gru_k<<<dim3(B_, 2), 256, 0, stream>>>(gi, gh, last_h, out, xcat_bf);

    proj_mfma_k<<<V_ / 64, 256, 0, stream>>>(xcat_bf, proj_W, proj_b, gen);

    enc_mfma_dot_k<<<g2, 256, 0, stream>>>(enc_bf, Wb_copy, copy1_b, 0, out, 1, rawb);

    copy_epi_k<<<B_, T_, 0, stream>>>(rawb, u_input, scat, sc4);
    gen_stats_k<<<dim3(B_, NS_), 256, 0, stream>>>(gen, mpart, lpart);
    combine2_k<<<1, B_, 0, stream>>>(mpart, lpart, sc4, params);

    float* proba = out + 2 * B_ * H_;
    write_k<<<dim3((VT_ / 4 + 255) / 256, B_), 256, 0, stream>>>(gen, params, proba);
    fix_k<<<B_, T_, 0, stream>>>(gen, scat, u_input, params, proba);
}